// Round 17
// baseline (668.635 us; speedup 1.0000x reference)
//
#include <hip/hip_runtime.h>
#include <math.h>

#define B_ 2
#define C_ 8
#define M_ 8
#define NH_ 8
#define F_ 1024
#define W_ 512
#define HD_ 128
#define FW 524288L  // F_*W_
#define PF_ 1026
#define PW_ 514

typedef __bf16 bf16_t;
typedef __bf16 bf16x8 __attribute__((ext_vector_type(8)));
typedef __bf16 bf16x4 __attribute__((ext_vector_type(4)));
typedef float f32x4 __attribute__((ext_vector_type(4)));

__device__ __forceinline__ void gload16(const void* g, void* l) {
    __builtin_amdgcn_global_load_lds(
        (const __attribute__((address_space(1))) unsigned int*)g,
        (__attribute__((address_space(3))) unsigned int*)l,
        16, 0, 0);
}

__device__ __forceinline__ float gelu_f(float v) {
    return 0.5f * v * (1.0f + erff(v * 0.70710678118f));
}

// bijective XCD-chunked block swizzle (requires nwg % 8 == 0)
__device__ __forceinline__ void xcd_swz3(int& bx, int& by, int& bz) {
    const int nwg = gridDim.x * gridDim.y * gridDim.z;
    int orig = blockIdx.x + gridDim.x * (blockIdx.y + gridDim.y * blockIdx.z);
    orig = (orig & 7) * (nwg >> 3) + (orig >> 3);
    bx = orig % gridDim.x;
    int t = orig / gridDim.x;
    by = t % gridDim.y;
    bz = t / gridDim.y;
}

// ---------------- fused prep: cvtw | pad_stage | aprep | border-zero ----------------
__global__ __launch_bounds__(256)
void prep_k(const float* __restrict__ q_pw, const float* __restrict__ k_pw,
            const float* __restrict__ v_pw, const float* __restrict__ o_pw,
            const float* __restrict__ x,
            const float* __restrict__ qw, const float* __restrict__ kw,
            const float* __restrict__ vw, const float* __restrict__ ow,
            const float* __restrict__ c1w, const float* __restrict__ c2w,
            const float* __restrict__ qb, const float* __restrict__ kb,
            const float* __restrict__ vb,
            bf16_t* __restrict__ W4, bf16_t* __restrict__ px,
            bf16_t* __restrict__ a_qkv, bf16_t* __restrict__ a_op,
            bf16_t* __restrict__ a_c1, bf16_t* __restrict__ a_c2,
            float* __restrict__ bias_qkv,
            bf16_t* __restrict__ p8a, bf16_t* __restrict__ p8b, bf16_t* __restrict__ p32)
{
    const int bid = blockIdx.x, tid = threadIdx.x;
    if (bid < 32768) {
        long i = (long)bid * 256 + tid;
        const int wsel = (int)(i >> 21);
        const long off = i & 2097151L;
        const float* src = (wsel == 0) ? q_pw : (wsel == 1) ? k_pw : (wsel == 2) ? v_pw : o_pw;
        float4 v = ((const float4*)src)[off];
        bf16x4 r = { (bf16_t)v.x, (bf16_t)v.y, (bf16_t)v.z, (bf16_t)v.w };
        *(bf16x4*)&W4[i * 4] = r;
    } else if (bid < 36889) {
        long i = (long)(bid - 32768) * 256 + tid;
        if (i >= (long)B_ * PF_ * PW_) return;
        int wc = (int)(i % PW_);
        long t = i / PW_;
        int fr = (int)(t % PF_);
        int b  = (int)(t / PF_);
        bf16x8 v = {};
        if (fr >= 1 && fr <= F_ && wc >= 1 && wc <= W_) {
            const float* s = x + (long)b * 8 * FW + (long)(fr - 1) * W_ + (wc - 1);
            #pragma unroll
            for (int c = 0; c < 8; ++c) v[c] = (bf16_t)s[c * FW];
        }
        *(bf16x8*)&px[i * 8] = v;
    } else if (bid < 36961) {
        int sub = bid - 36889;
        int mode = sub / 18;
        int i = (sub % 18) * 256 + tid;
        if (mode == 0) {              // qkv: [3][32][32]
            if (i < 3072) {
                int k = i & 31, co = (i >> 5) & 31, df = i >> 10;
                int tap = k >> 3, ci = k & 7;
                float v = 0.f;
                if (tap < 3) {
                    if (co < 8)       v = qw[((co * 8 + ci) * 3 + df) * 3 + tap];
                    else if (co < 16) v = kw[(((co - 8) * 8 + ci) * 3 + df) * 3 + tap];
                    else if (co < 24) v = vw[(((co - 16) * 8 + ci) * 3 + df) * 3 + tap];
                }
                a_qkv[i] = (bf16_t)v;
            }
            if (i < 32) bias_qkv[i] = (i < 8) ? qb[i] : (i < 16) ? kb[i - 8] : (i < 24) ? vb[i - 16] : 0.f;
        } else if (mode == 1) {       // oproj: [3][16][64]
            if (i < 3072) {
                int k = i & 63, co = (i >> 6) & 15, df = i >> 10;
                int src = k >> 5, r = k & 31, tap = r >> 3, ci = src * 8 + (r & 7);
                float v = 0.f;
                if (co < 8 && tap < 3) v = ow[((co * 16 + ci) * 3 + df) * 3 + tap];
                a_op[i] = (bf16_t)v;
            }
        } else if (mode == 2) {       // c1: [3][32][32]
            if (i < 3072) {
                int k = i & 31, co = (i >> 5) & 31, df = i >> 10;
                int tap = k >> 3, ci = k & 7;
                float v = (tap < 3) ? c1w[((co * 8 + ci) * 3 + df) * 3 + tap] : 0.f;
                a_c1[i] = (bf16_t)v;
            }
        } else {                      // c2: [3][16][96]
            if (i < 4608) {
                int k = i % 96, co = (i / 96) & 15, df = i / (96 * 16);
                int tap = k >> 5, ci = k & 31;
                float v = (co < 8) ? c2w[((co * 32 + ci) * 3 + df) * 3 + tap] : 0.f;
                a_c2[i] = (bf16_t)v;
            }
        }
    } else {
        int i = (bid - 36961) * 256 + tid;
        if (i >= 2 * 3076) return;
        int b = i / 3076, p = i % 3076;
        int fr, wc;
        if (p < 514)       { fr = 0;    wc = p; }
        else if (p < 1028) { fr = 1025; wc = p - 514; }
        else if (p < 2052) { fr = 1 + (p - 1028); wc = 0; }
        else               { fr = 1 + (p - 2052); wc = 513; }
        long pix = ((long)b * PF_ + fr) * PW_ + wc;
        bf16x8 z = {};
        *(bf16x8*)&p8a[pix * 8] = z;
        *(bf16x8*)&p8b[pix * 8] = z;
        #pragma unroll
        for (int k = 0; k < 4; ++k) *(bf16x8*)&p32[pix * 32 + k * 8] = z;
    }
}

// ---------------- MFMA shift-GEMM conv ----------------
template<int CIN, int KSTEPS, int MFRAGS, int DUAL, int EPI, int RESBF>
__global__ __launch_bounds__(256)
void convg_k(const bf16_t* __restrict__ px0, const bf16_t* __restrict__ px1,
             const bf16_t* __restrict__ Ab, const float* __restrict__ bias,
             const void* __restrict__ resid, void* __restrict__ outp)
{
    const int f = blockIdx.y, b = blockIdx.z;
    const int tid = threadIdx.x, lane = tid & 63, wid = tid >> 6;
    const int l15 = lane & 15, l4 = lane >> 4;
    const int wbase = blockIdx.x * 256 + wid * 64;
    const int KW = KSTEPS * 32, M16 = MFRAGS * 16;

    bf16x8 af[3][MFRAGS][KSTEPS];
    #pragma unroll
    for (int df = 0; df < 3; ++df)
        #pragma unroll
        for (int mf = 0; mf < MFRAGS; ++mf)
            #pragma unroll
            for (int kk = 0; kk < KSTEPS; ++kk)
                af[df][mf][kk] = *(const bf16x8*)&Ab[(long)(df * M16 + mf * 16 + l15) * KW + kk * 32 + l4 * 8];

    f32x4 acc[MFRAGS][4];
    #pragma unroll
    for (int mf = 0; mf < MFRAGS; ++mf)
        #pragma unroll
        for (int nf = 0; nf < 4; ++nf)
            acc[mf][nf] = (f32x4){0.f, 0.f, 0.f, 0.f};

    #pragma unroll
    for (int df = 0; df < 3; ++df) {
        const long rowb = ((long)(b * PF_ + f + df)) * PW_ * CIN;
        #pragma unroll
        for (int nf = 0; nf < 4; ++nf) {
            const int wp = wbase + nf * 16 + l15;
            #pragma unroll
            for (int kk = 0; kk < KSTEPS; ++kk) {
                const bf16_t* src = (DUAL && kk == 1) ? px1 : px0;
                long addr = (CIN == 8) ? rowb + (long)(wp + l4) * 8
                                       : rowb + (long)(wp + kk) * 32 + l4 * 8;
                bf16x8 bv = *(const bf16x8*)&src[addr];
                #pragma unroll
                for (int mf = 0; mf < MFRAGS; ++mf)
                    acc[mf][nf] = __builtin_amdgcn_mfma_f32_16x16x32_bf16(
                        af[df][mf][kk], bv, acc[mf][nf], 0, 0, 0);
            }
        }
    }

    #pragma unroll
    for (int mf = 0; mf < MFRAGS; ++mf) {
        #pragma unroll
        for (int nf = 0; nf < 4; ++nf) {
            const int wp = wbase + nf * 16 + l15;
            if (EPI == 2) {
                const int cob = mf * 16 + l4 * 4;
                bf16x4 ov;
                #pragma unroll
                for (int r = 0; r < 4; ++r)
                    ov[r] = (bf16_t)gelu_f(acc[mf][nf][r] + bias[cob + r]);
                *(bf16x4*)&((bf16_t*)outp)[(((long)(b * PF_ + f + 1)) * PW_ + wp + 1) * 32 + cob] = ov;
            } else {
                #pragma unroll
                for (int r = 0; r < 4; ++r) {
                    const int co = mf * 16 + l4 * 4 + r;
                    float v = acc[mf][nf][r];
                    if (EPI == 0) {
                        if (co < 24)
                            ((bf16_t*)outp)[((long)(b * 24 + co)) * FW + (long)f * W_ + wp] = (bf16_t)(v + bias[co]);
                    } else {
                        if (co < 8) {
                            long oi = ((long)(b * 8 + co)) * FW + (long)f * W_ + wp;
                            float rv = RESBF ? (float)((const bf16_t*)resid)[oi]
                                             : ((const float*)resid)[oi];
                            ((bf16_t*)outp)[oi] = (bf16_t)(v + bias[co] + rv);
                        }
                    }
                }
            }
        }
    }
}

// ---------------- bf16 MFMA GEMM: C = A(MxK) * B^T-stored(NxK) ----------------
template<int OUTBF>
__global__ __launch_bounds__(256, 4)
void gemm_mfma_k(const bf16_t* __restrict__ Ab, const bf16_t* __restrict__ Bb,
                 void* __restrict__ Cb,
                 int Kdim, int lda, int ldb, int ldc,
                 long sA, long sB, long sC_hi, long sC_lo, int zdivC, int aMod)
{
    __shared__ bf16_t sAt[8192];
    __shared__ bf16_t sBt[8192];

    int bx, by, bz;
    xcd_swz3(bx, by, bz);
    const int z = bz;
    const int m0 = by * 128;
    const int n0 = bx * 128;
    const int tid = threadIdx.x;
    const int lane = tid & 63, wid = tid >> 6;
    const int wr = (wid >> 1) * 64, wc = (wid & 1) * 64;
    const int l15 = lane & 15, l4 = lane >> 4;

    const bf16_t* A = Ab + (long)(z % aMod) * sA;
    const bf16_t* B = Bb + (long)z * sB;

    f32x4 acc[4][4];
    #pragma unroll
    for (int m = 0; m < 4; ++m)
        #pragma unroll
        for (int n = 0; n < 4; ++n)
            acc[m][n] = (f32x4){0.f, 0.f, 0.f, 0.f};

    const int grow = wid * 8 + (lane >> 3);
    const int gslot = lane & 7;

    for (int k0 = 0; k0 < Kdim; k0 += 64) {
        __syncthreads();
        #pragma unroll
        for (int r = 0; r < 4; ++r) {
            const int row = r * 32 + grow;
            gload16(A + (long)(m0 + row) * lda + k0 + ((gslot ^ (row & 7)) << 3),
                    sAt + r * 2048 + wid * 512);
        }
        #pragma unroll
        for (int r = 0; r < 4; ++r) {
            const int row = r * 32 + grow;
            gload16(B + (long)(n0 + row) * ldb + k0 + ((gslot ^ (row & 7)) << 3),
                    sBt + r * 2048 + wid * 512);
        }
        __syncthreads();

        bf16x8 afr[4][2], bfr[4][2];
        #pragma unroll
        for (int m = 0; m < 4; ++m) {
            const int row = wr + m * 16 + l15, swz = row & 7;
            afr[m][0] = *(const bf16x8*)&sAt[row * 64 + ((l4 ^ swz) << 3)];
            afr[m][1] = *(const bf16x8*)&sAt[row * 64 + (((4 + l4) ^ swz) << 3)];
        }
        #pragma unroll
        for (int n = 0; n < 4; ++n) {
            const int row = wc + n * 16 + l15, swz = row & 7;
            bfr[n][0] = *(const bf16x8*)&sBt[row * 64 + ((l4 ^ swz) << 3)];
            bfr[n][1] = *(const bf16x8*)&sBt[row * 64 + (((4 + l4) ^ swz) << 3)];
        }
        #pragma unroll
        for (int kk = 0; kk < 2; ++kk)
            #pragma unroll
            for (int m = 0; m < 4; ++m)
                #pragma unroll
                for (int n = 0; n < 4; ++n)
                    acc[m][n] = __builtin_amdgcn_mfma_f32_16x16x32_bf16(
                        afr[m][kk], bfr[n][kk], acc[m][n], 0, 0, 0);
    }

    const long zc = (long)(z / zdivC) * sC_hi + (long)(z % zdivC) * sC_lo;
    #pragma unroll
    for (int m = 0; m < 4; ++m) {
        #pragma unroll
        for (int n = 0; n < 4; ++n) {
            #pragma unroll
            for (int r = 0; r < 4; ++r) {
                int row = m0 + wr + m * 16 + l4 * 4 + r;
                int col = n0 + wc + n * 16 + l15;
                float v = acc[m][n][r];
                long cidx = zc + (long)row * ldc + col;
                if (OUTBF) ((bf16_t*)Cb)[cidx] = (bf16_t)v;
                else       ((float*)Cb)[cidx]  = v;
            }
        }
    }
}

// ---------------- merged q/k/v mclin GEMM (z = path*16 + bm), rope fused for q/k ----------------
__global__ __launch_bounds__(256, 4)
void qkvgemm_k(const bf16_t* __restrict__ W4, const bf16_t* __restrict__ XT,
               bf16_t* __restrict__ outp /* = QR base; KR/VL adjacent */)
{
    __shared__ bf16_t sAt[8192];
    __shared__ bf16_t sBt[8192];

    int bx, by, bz;
    xcd_swz3(bx, by, bz);
    const int zz = bz;                   // 0..47
    const int path = zz >> 4, bm = zz & 15;
    const bf16_t* A = W4 + (long)(path * 8 + (bm & 7)) * 1048576L;
    const bf16_t* B = XT + (long)zz * FW;   // [W][F], ldb = 1024
    const int m0 = by * 128;
    const int n0 = bx * 128;
    const int tid = threadIdx.x;
    const int lane = tid & 63, wid = tid >> 6;
    const int wr = (wid >> 1) * 64, wc = (wid & 1) * 64;
    const int l15 = lane & 15, l4 = lane >> 4;

    f32x4 acc[4][4];
    #pragma unroll
    for (int m = 0; m < 4; ++m)
        #pragma unroll
        for (int n = 0; n < 4; ++n)
            acc[m][n] = (f32x4){0.f, 0.f, 0.f, 0.f};

    const int grow = wid * 8 + (lane >> 3);
    const int gslot = lane & 7;

    for (int k0 = 0; k0 < 1024; k0 += 64) {
        __syncthreads();
        #pragma unroll
        for (int r = 0; r < 4; ++r) {
            const int row = r * 32 + grow;
            gload16(A + (long)(m0 + row) * 1024 + k0 + ((gslot ^ (row & 7)) << 3),
                    sAt + r * 2048 + wid * 512);
        }
        #pragma unroll
        for (int r = 0; r < 4; ++r) {
            const int row = r * 32 + grow;
            gload16(B + (long)(n0 + row) * 1024 + k0 + ((gslot ^ (row & 7)) << 3),
                    sBt + r * 2048 + wid * 512);
        }
        __syncthreads();

        bf16x8 afr[4][2], bfr[4][2];
        #pragma unroll
        for (int m = 0; m < 4; ++m) {
            const int row = wr + m * 16 + l15, swz = row & 7;
            afr[m][0] = *(const bf16x8*)&sAt[row * 64 + ((l4 ^ swz) << 3)];
            afr[m][1] = *(const bf16x8*)&sAt[row * 64 + (((4 + l4) ^ swz) << 3)];
        }
        #pragma unroll
        for (int n = 0; n < 4; ++n) {
            const int row = wc + n * 16 + l15, swz = row & 7;
            bfr[n][0] = *(const bf16x8*)&sBt[row * 64 + ((l4 ^ swz) << 3)];
            bfr[n][1] = *(const bf16x8*)&sBt[row * 64 + (((4 + l4) ^ swz) << 3)];
        }
        #pragma unroll
        for (int kk = 0; kk < 2; ++kk)
            #pragma unroll
            for (int m = 0; m < 4; ++m)
                #pragma unroll
                for (int n = 0; n < 4; ++n)
                    acc[m][n] = __builtin_amdgcn_mfma_f32_16x16x32_bf16(
                        afr[m][kk], bfr[n][kk], acc[m][n], 0, 0, 0);
    }

    if (path < 2) {
        const long base = (long)path * 8388608L + (((long)bm * 8 + by) * 512L) * 128L;
        #pragma unroll
        for (int m = 0; m < 4; ++m) {
            const int d0 = wr + m * 16 + l4 * 4;
            const float inv0 = __expf(-(float)(d0 >> 1) * 0.14391156507f);
            const float inv1 = __expf(-(float)((d0 >> 1) + 1) * 0.14391156507f);
            #pragma unroll
            for (int n = 0; n < 4; ++n) {
                const int col = n0 + wc + n * 16 + l15;
                float s0, c0, s1, c1;
                __sincosf((float)col * inv0, &s0, &c0);
                __sincosf((float)col * inv1, &s1, &c1);
                float v0 = acc[m][n][0], v1 = acc[m][n][1];
                float v2 = acc[m][n][2], v3 = acc[m][n][3];
                bf16x4 ov = { (bf16_t)(v0 * c0 - v1 * s0), (bf16_t)(v1 * c0 + v0 * s0),
                              (bf16_t)(v2 * c1 - v3 * s1), (bf16_t)(v3 * c1 + v2 * s1) };
                *(bf16x4*)&outp[base + (long)col * 128 + d0] = ov;
            }
        }
    } else {
        const long base = 16777216L + (long)bm * FW;
        #pragma unroll
        for (int m = 0; m < 4; ++m)
            #pragma unroll
            for (int n = 0; n < 4; ++n)
                #pragma unroll
                for (int r = 0; r < 4; ++r) {
                    int row = m0 + wr + m * 16 + l4 * 4 + r;
                    int col = n0 + wc + n * 16 + l15;
                    outp[base + (long)row * 512 + col] = (bf16_t)acc[m][n][r];
                }
    }
}

// ---------------- fused attention (64-row m-tiles + T14 async reg-prefetch) ----------------
// Phase A: per segment s (kc,k0-half): prefetch next Q/K chunk into regs before MFMA;
//          ds_write after barrier. Per kc epilogue: S store + online stats.
// Phase B: same for V tiles; P computed from S (L2-hot) into LDS.
__global__ __launch_bounds__(256, 4)
void attn_k(const bf16_t* __restrict__ QR, const bf16_t* __restrict__ KR,
            const bf16_t* __restrict__ VL, const float* __restrict__ prevb,
            float* __restrict__ Sout, bf16_t* __restrict__ AT)
{
    __shared__ bf16_t sA[4096];    // Q 64x64 / P 64x64, swizzled
    __shared__ bf16_t sB[8192];    // K/V 128x64, swizzled
    __shared__ float red[2][64][2];
    __shared__ float Mrun[64], Srun[64];

    int bx, by, bz;
    xcd_swz3(bx, by, bz);
    (void)by;
    const int z = bz;
    const int m0 = bx * 64;
    const bf16_t* Qb = QR + (long)z * 65536L;
    const bf16_t* Kb = KR + (long)z * 65536L;
    const bf16_t* Vb = VL + (long)z * 65536L;
    const float* prev = prevb + (long)z * 262144L;
    float* Sb = Sout + (long)z * 262144L;

    const int tid = threadIdx.x, lane = tid & 63, wid = tid >> 6;
    const int l15 = lane & 15, l4 = lane >> 4;
    const int wr = (wid >> 1) * 32, wc = (wid & 1) * 64;
    const int grow = wid * 8 + (lane >> 3);
    const int gslot = lane & 7;

    if (tid < 64) { Mrun[tid] = -1e30f; Srun[tid] = 0.f; }

    // ---------------- phase A: S = QK^T/32 + prev ----------------
    bf16x8 qpre[2], kpre[4];
    // prologue: prefetch segment 0 (kc=0, k0=0)
    #pragma unroll
    for (int r = 0; r < 2; ++r)
        qpre[r] = *(const bf16x8*)&Qb[(long)(m0 + r * 32 + grow) * 128 + gslot * 8];
    #pragma unroll
    for (int r = 0; r < 4; ++r)
        kpre[r] = *(const bf16x8*)&Kb[(long)(r * 32 + grow) * 128 + gslot * 8];

    f32x4 acc[2][4];
    #pragma unroll
    for (int m = 0; m < 2; ++m)
        #pragma unroll
        for (int n = 0; n < 4; ++n)
            acc[m][n] = (f32x4){0.f, 0.f, 0.f, 0.f};

    for (int s = 0; s < 8; ++s) {
        __syncthreads();   // previous segment's LDS reads complete
        // commit prefetched regs -> LDS (swizzled dest, linear src)
        #pragma unroll
        for (int r = 0; r < 2; ++r) {
            const int row = r * 32 + grow;
            *(bf16x8*)&sA[row * 64 + ((gslot ^ (row & 7)) << 3)] = qpre[r];
        }
        #pragma unroll
        for (int r = 0; r < 4; ++r) {
            const int row = r * 32 + grow;
            *(bf16x8*)&sB[row * 64 + ((gslot ^ (row & 7)) << 3)] = kpre[r];
        }
        // issue next segment's loads (hidden under MFMA below)
        if (s < 7) {
            const int ns = s + 1;
            const int nkc = ns >> 1, nk0 = (ns & 1) * 64;
            #pragma unroll
            for (int r = 0; r < 2; ++r)
                qpre[r] = *(const bf16x8*)&Qb[(long)(m0 + r * 32 + grow) * 128 + nk0 + gslot * 8];
            #pragma unroll
            for (int r = 0; r < 4; ++r)
                kpre[r] = *(const bf16x8*)&Kb[(long)(nkc * 128 + r * 32 + grow) * 128 + nk0 + gslot * 8];
        }
        __syncthreads();   // sA/sB ready

        bf16x8 afr[2][2], bfr[4][2];
        #pragma unroll
        for (int m = 0; m < 2; ++m) {
            const int row = wr + m * 16 + l15, swz = row & 7;
            afr[m][0] = *(const bf16x8*)&sA[row * 64 + ((l4 ^ swz) << 3)];
            afr[m][1] = *(const bf16x8*)&sA[row * 64 + (((4 + l4) ^ swz) << 3)];
        }
        #pragma unroll
        for (int n = 0; n < 4; ++n) {
            const int row = wc + n * 16 + l15, swz = row & 7;
            bfr[n][0] = *(const bf16x8*)&sB[row * 64 + ((l4 ^ swz) << 3)];
            bfr[n][1] = *(const bf16x8*)&sB[row * 64 + (((4 + l4) ^ swz) << 3)];
        }
        __builtin_amdgcn_s_setprio(1);
        #pragma unroll
        for (int kk = 0; kk < 2; ++kk)
            #pragma unroll
            for (int m = 0; m < 2; ++m)
                #pragma unroll
                for (int n = 0; n < 4; ++n)
                    acc[m][n] = __builtin_amdgcn_mfma_f32_16x16x32_bf16(
                        afr[m][kk], bfr[n][kk], acc[m][n], 0, 0, 0);
        __builtin_amdgcn_s_setprio(0);

        if (s & 1) {
            // epilogue for kc = s>>1: add prev, store S, per-row stats
            const int kc = s >> 1;
            #pragma unroll
            for (int m = 0; m < 2; ++m) {
                #pragma unroll
                for (int n = 0; n < 4; ++n) {
                    #pragma unroll
                    for (int r = 0; r < 4; ++r) {
                        int row = m0 + wr + m * 16 + l4 * 4 + r;
                        int col = kc * 128 + wc + n * 16 + l15;
                        float v = acc[m][n][r] * 0.03125f + prev[(long)row * 512 + col];
                        acc[m][n][r] = v;
                        Sb[(long)row * 512 + col] = v;
                    }
                }
            }
            #pragma unroll
            for (int m = 0; m < 2; ++m) {
                #pragma unroll
                for (int r = 0; r < 4; ++r) {
                    float mx = -1e30f;
                    #pragma unroll
                    for (int n = 0; n < 4; ++n) mx = fmaxf(mx, acc[m][n][r]);
                    #pragma unroll
                    for (int o = 1; o <= 8; o <<= 1) mx = fmaxf(mx, __shfl_xor(mx, o, 64));
                    float se = 0.f;
                    #pragma unroll
                    for (int n = 0; n < 4; ++n) se += __expf(acc[m][n][r] - mx);
                    #pragma unroll
                    for (int o = 1; o <= 8; o <<= 1) se += __shfl_xor(se, o, 64);
                    if (l15 == 0) {
                        int row = wr + m * 16 + l4 * 4 + r;
                        red[wid & 1][row][0] = mx;
                        red[wid & 1][row][1] = se;
                    }
                }
            }
            __syncthreads();
            if (tid < 64) {
                float ma = red[0][tid][0], sa = red[0][tid][1];
                float mb = red[1][tid][0], sb = red[1][tid][1];
                float mt = fmaxf(ma, mb);
                float st = sa * __expf(ma - mt) + sb * __expf(mb - mt);
                float M0 = Mrun[tid], S0 = Srun[tid];
                float M1 = fmaxf(M0, mt);
                Srun[tid] = S0 * __expf(M0 - M1) + st * __expf(mt - M1);
                Mrun[tid] = M1;
            }
            // reset accumulator for next kc
            #pragma unroll
            for (int m = 0; m < 2; ++m)
                #pragma unroll
                for (int n = 0; n < 4; ++n)
                    acc[m][n] = (f32x4){0.f, 0.f, 0.f, 0.f};
        }
    }
    __syncthreads();

    // ---------------- phase B: O = softmax(S) @ V ----------------
    f32x4 oacc[2][4];
    #pragma unroll
    for (int m = 0; m < 2; ++m)
        #pragma unroll
        for (int n = 0; n < 4; ++n)
            oacc[m][n] = (f32x4){0.f, 0.f, 0.f, 0.f};

    const int prow0 = tid >> 4, pl = tid & 15;

    bf16x8 vpre[4];
    // prologue: prefetch V tile 0
    #pragma unroll
    for (int r = 0; r < 4; ++r)
        vpre[r] = *(const bf16x8*)&Vb[(long)(r * 32 + grow) * 512 + gslot * 8];

    for (int t = 0; t < 8; ++t) {
        const int kt = t * 64;
        // compute P(t) into regs (S is L2-hot; overlaps prior MFMA drain)
        bf16x4 e[4];
        #pragma unroll
        for (int p = 0; p < 4; ++p) {
            const int row = p * 16 + prow0;
            float4 v = *(const float4*)(Sb + (long)(m0 + row) * 512 + kt + pl * 4);
            float mr = Mrun[row];
            e[p] = (bf16x4){ (bf16_t)__expf(v.x - mr), (bf16_t)__expf(v.y - mr),
                             (bf16_t)__expf(v.z - mr), (bf16_t)__expf(v.w - mr) };
        }
        __syncthreads();   // previous tile's LDS reads complete
        #pragma unroll
        for (int p = 0; p < 4; ++p) {
            const int row = p * 16 + prow0;
            *(bf16x4*)((char*)sA + row * 128 + ((((pl >> 1) ^ (row & 7))) << 4) + (pl & 1) * 8) = e[p];
        }
        #pragma unroll
        for (int r = 0; r < 4; ++r) {
            const int row = r * 32 + grow;
            *(bf16x8*)&sB[row * 64 + ((gslot ^ (row & 7)) << 3)] = vpre[r];
        }
        if (t < 7) {
            const int nkt = kt + 64;
            #pragma unroll
            for (int r = 0; r < 4; ++r)
                vpre[r] = *(const bf16x8*)&Vb[(long)(r * 32 + grow) * 512 + nkt + gslot * 8];
        }
        __syncthreads();   // sA/sB ready

        bf16x8 afr[2][2], bfr[4][2];
        #pragma unroll
        for (int m = 0; m < 2; ++m) {
            const int row = wr + m * 16 + l15, swz = row & 7;
            afr[m][0] = *(const bf16x8*)&sA[row * 64 + ((l4 ^ swz) << 3)];
            afr[m][1] = *(const bf16x8*)&sA[row * 64 + (((4 + l4) ^ swz) << 3)];
        }
        #pragma unroll
        for (int n = 0; n < 4; ++n) {
            const int row = wc + n * 16 + l15, swz = row & 7;
            bfr[n][0] = *(const bf16x8*)&sB[row * 64 + ((l4 ^ swz) << 3)];
            bfr[n][1] = *(const bf16x8*)&sB[row * 64 + (((4 + l4) ^ swz) << 3)];
        }
        __builtin_amdgcn_s_setprio(1);
        #pragma unroll
        for (int kk = 0; kk < 2; ++kk)
            #pragma unroll
            for (int m = 0; m < 2; ++m)
                #pragma unroll
                for (int n = 0; n < 4; ++n)
                    oacc[m][n] = __builtin_amdgcn_mfma_f32_16x16x32_bf16(
                        afr[m][kk], bfr[n][kk], oacc[m][n], 0, 0, 0);
        __builtin_amdgcn_s_setprio(0);
    }

    const long base = (long)(z >> 3) * FW + (long)(z & 7) * 128L;
    #pragma unroll
    for (int m = 0; m < 2; ++m) {
        #pragma unroll
        for (int n = 0; n < 4; ++n) {
            #pragma unroll
            for (int r = 0; r < 4; ++r) {
                const int row = wr + m * 16 + l4 * 4 + r;
                const int col = wc + n * 16 + l15;
                float v = oacc[m][n][r] / Srun[row];
                AT[base + (long)(m0 + row) * 1024 + col] = (bf16_t)v;
            }
        }
    }
}

// ---------------- transpose+cvt: QKV planar [b][24][F][W] -> XT48 [path*16+bm][W][F] ----------------
__global__ __launch_bounds__(256)
void tcvt_k(const bf16_t* __restrict__ in, bf16_t* __restrict__ outp)
{
    __shared__ float tile[32][33];
    const int w0 = blockIdx.x * 32, f0 = blockIdx.y * 32;
    const int z = blockIdx.z;              // 0..47
    const int path = z >> 4, bm = z & 15;
    const int inSlice = (bm >> 3) * 24 + path * 8 + (bm & 7);
    const long ibase = (long)inSlice * FW;
    const long obase = (long)z * FW;
    const int tx = threadIdx.x & 31, ty = threadIdx.x >> 5;
    #pragma unroll
    for (int i = 0; i < 4; ++i)
        tile[ty + i * 8][tx] = (float)in[ibase + (long)(f0 + ty + i * 8) * W_ + w0 + tx];
    __syncthreads();
    #pragma unroll
    for (int i = 0; i < 4; ++i)
        outp[obase + (long)(w0 + ty + i * 8) * F_ + f0 + tx] = (bf16_t)tile[tx][ty + i * 8];
}

// ---------------- depthwise o_dw mix (bf16 in) -> channels-last bf16 ----------------
__global__ __launch_bounds__(256)
void odw_k(const bf16_t* __restrict__ t, const float* __restrict__ dw, bf16_t* __restrict__ px)
{
    long i = (long)blockIdx.x * 256 + threadIdx.x;
    int w = (int)(i & (W_ - 1));
    long q = i >> 9;
    int f = (int)(q & (F_ - 1));
    int b = (int)(q >> 10);
    const bf16_t* s = t + (long)b * 8 * FW + (long)f * W_ + w;
    float tv[8];
    #pragma unroll
    for (int c = 0; c < 8; ++c) tv[c] = (float)s[c * FW];
    bf16x8 o;
    #pragma unroll
    for (int d = 0; d < 8; ++d) {
        float a = 0.f;
        #pragma unroll
        for (int c = 0; c < 8; ++c) a += tv[c] * dw[d * 8 + c];
        o[d] = (bf16_t)a;
    }
    *(bf16x8*)&px[(((long)b * PF_ + f + 1) * PW_ + w + 1) * 8] = o;
}

// ---------------- multichannel layernorm over F axis ----------------
template<typename TIN, int O1BF>
__global__ __launch_bounds__(256)
void mcln_k(const TIN* __restrict__ in, const float* __restrict__ gam,
            const float* __restrict__ bet, void* __restrict__ o1, float* __restrict__ o2,
            bf16_t* __restrict__ px)
{
    int wi = threadIdx.x & 31, fg = threadIdx.x >> 5;
    int w0 = blockIdx.x * 32;
    int c = blockIdx.y, b = blockIdx.z;
    long base = ((long)b * C_ + c) * FW + w0 + wi;
    float s = 0.f, q = 0.f;
    for (int f = fg; f < F_; f += 8) {
        float v = (float)in[base + (long)f * W_];
        s += v; q += v * v;
    }
    __shared__ float rs[8][33], rq[8][33];
    __shared__ float mu_s[32], inv_s[32];
    rs[fg][wi] = s; rq[fg][wi] = q;
    __syncthreads();
    if (fg == 0) {
        float ts = 0.f, tq = 0.f;
        for (int g = 0; g < 8; ++g) { ts += rs[g][wi]; tq += rq[g][wi]; }
        float mu = ts * (1.0f / F_);
        float var = tq * (1.0f / F_) - mu * mu;
        mu_s[wi] = mu;
        inv_s[wi] = rsqrtf(var + 1e-5f);
    }
    __syncthreads();
    float mu = mu_s[wi], inv = inv_s[wi];
    for (int f = fg; f < F_; f += 8) {
        float v = (float)in[base + (long)f * W_];
        float r = (v - mu) * inv * gam[c * F_ + f] + bet[c * F_ + f];
        long oi = base + (long)f * W_;
        if (O1BF) ((bf16_t*)o1)[oi] = (bf16_t)r;
        else      ((float*)o1)[oi]  = r;
        if (o2) o2[oi] = r;
        if (px) px[(((long)b * PF_ + f + 1) * PW_ + (w0 + wi) + 1) * 8 + c] = (bf16_t)r;
    }
}

extern "C" void kernel_launch(void* const* d_in, const int* in_sizes, int n_in,
                              void* d_out, int out_size, void* d_ws, size_t ws_size,
                              hipStream_t stream) {
    (void)in_sizes; (void)n_in; (void)out_size; (void)ws_size;
    const float* x        = (const float*)d_in[0];
    const float* prev_qk  = (const float*)d_in[1];
    const float* qconv_w  = (const float*)d_in[2];
    const float* qconv_b  = (const float*)d_in[3];
    const float* q_pw     = (const float*)d_in[4];
    const float* kconv_w  = (const float*)d_in[5];
    const float* kconv_b  = (const float*)d_in[6];
    const float* k_pw     = (const float*)d_in[7];
    const float* vconv_w  = (const float*)d_in[8];
    const float* vconv_b  = (const float*)d_in[9];
    const float* v_pw     = (const float*)d_in[10];
    const float* o_pw     = (const float*)d_in[11];
    const float* o_dw     = (const float*)d_in[12];
    const float* oproj_w  = (const float*)d_in[13];
    const float* oproj_b  = (const float*)d_in[14];
    const float* n1_w     = (const float*)d_in[15];
    const float* n1_b     = (const float*)d_in[16];
    const float* c1_w     = (const float*)d_in[17];
    const float* c1_b     = (const float*)d_in[18];
    const float* c2_w     = (const float*)d_in[19];
    const float* c2_b     = (const float*)d_in[20];
    const float* n2_w     = (const float*)d_in[21];
    const float* n2_b     = (const float*)d_in[22];

    float* out    = (float*)d_out;
    float* qk_out = out + 16777216L;

    // -------- workspace layout (~338.5 MB) --------
    char* wsb = (char*)d_ws;
    bf16_t* PX8  = (bf16_t*)(wsb + 0L);            // 16,876,032   A..F
    bf16_t* W4   = (bf16_t*)(wsb + 16876032L);     // 67,108,864   A..E
    bf16_t* QR   = (bf16_t*)(wsb + 83984896L);     // 16,777,216   C..D
    bf16_t* KR   = (bf16_t*)(wsb + 100762112L);    // 16,777,216   C..D
    bf16_t* VL   = (bf16_t*)(wsb + 117539328L);    // 16,777,216   C..D
    bf16_t* XT48 = (bf16_t*)(wsb + 134316544L);    // 50,331,648   C (dead after qkvgemm)
    bf16_t* HIDb = (bf16_t*)(wsb + 134316544L);    //   reuse XT48 head: 16,777,216  G..H
    bf16_t* QKV  = (bf16_t*)(wsb + 184648192L);    // 50,331,648   B..C (tcvt)
    bf16_t* AT   = (bf16_t*)(wsb + 184648192L);    //   reuse QKV head: 16,777,216   D..E
    bf16_t* F1b  = (bf16_t*)(wsb + 201425408L);    //   reuse QKV mid:  16,777,216   E
    bf16_t* PRE  = (bf16_t*)(wsb + 218202624L);    //   reuse QKV tail: 16,777,216   F..H
    bf16_t* PXA2 = (bf16_t*)(wsb + 234979840L);    // 16,875,776 fresh  (borders@prep) E..F
    bf16_t* PXH  = (bf16_t*)(wsb + 251855616L);    // 16,875,776 fresh  (borders@prep) G..H
    bf16_t* PXC1 = (bf16_t*)(wsb + 268731392L);    // 67,502,592 fresh  (borders@prep) H
    bf16_t* ABQ  = (bf16_t*)(wsb + 336233984L);
    bf16_t* ABO  = (bf16_t*)(wsb + 336233984L + 16384L);
    bf16_t* ABC1 = (bf16_t*)(wsb + 336233984L + 32768L);
    bf16_t* ABC2 = (bf16_t*)(wsb + 336233984L + 49152L);
    float*  BQKV = (float*) (wsb + 336233984L + 65536L);

    const dim3 cvgrid(2, F_, B_);
    const dim3 tgrid(16, 32, 48);

    // ---- A: fused prep ----
    prep_k<<<36986, 256, 0, stream>>>(q_pw, k_pw, v_pw, o_pw, x,
                                      qconv_w, kconv_w, vconv_w, oproj_w, c1_w, c2_w,
                                      qconv_b, kconv_b, vconv_b,
                                      W4, PX8, ABQ, ABO, ABC1, ABC2, BQKV,
                                      PXA2, PXH, PXC1);

    // ---- B: fused q/k/v conv (M=24) ----
    convg_k<8, 1, 2, 0, 0, 0><<<cvgrid, 256, 0, stream>>>(PX8, nullptr, ABQ, BQKV, nullptr, QKV);

    // ---- C: transpose once; merged q/k/v mclin (rope fused) ----
    tcvt_k<<<tgrid, 256, 0, stream>>>(QKV, XT48);
    qkvgemm_k<<<dim3(4, 8, 48), 256, 0, stream>>>(W4, XT48, QR);

    // ---- D: fused attention (QK^T + softmax + PV; async reg-prefetch) ----
    attn_k<<<dim3(8, 1, 128), 256, 0, stream>>>(QR, KR, VL, prev_qk, qk_out, AT);

    // ---- E: o linear (bf16 W4, bf16 out) + depthwise mix ----
    gemm_mfma_k<1><<<dim3(4, 8, 16), 256, 0, stream>>>(W4 + 25165824L, AT, F1b,
        F_, F_, F_, W_, 1048576L, 524288L, 524288L, 0L, 1, 8);
    odw_k<<<4096, 256, 0, stream>>>(F1b, o_dw, PXA2);

    // ---- F: oproj conv (x ++ a2) + x residual -> pre1 (bf16) ----
    convg_k<8, 2, 1, 1, 1, 0><<<cvgrid, 256, 0, stream>>>(PX8, PXA2, ABO, oproj_b, x, PRE);

    // ---- G: hid = mcln(pre1) -> HIDb bf16 + PXH channels-last bf16 ----
    mcln_k<bf16_t, 1><<<dim3(16, 8, 2), 256, 0, stream>>>(PRE, n1_w, n1_b, HIDb, nullptr, PXH);

    // ---- H: ffn ----
    convg_k<8, 1, 2, 0, 2, 0><<<cvgrid, 256, 0, stream>>>(PXH, nullptr, ABC1, c1_b, nullptr, PXC1);
    convg_k<32, 3, 1, 0, 1, 1><<<cvgrid, 256, 0, stream>>>(PXC1, nullptr, ABC2, c2_b, HIDb, PRE);
    mcln_k<bf16_t, 0><<<dim3(16, 8, 2), 256, 0, stream>>>(PRE, n2_w, n2_b, out, out + 8388608L, nullptr);
}

// Round 18
// 609.985 us; speedup vs baseline: 1.0961x; 1.0961x over previous
//
#include <hip/hip_runtime.h>
#include <math.h>

#define B_ 2
#define C_ 8
#define M_ 8
#define NH_ 8
#define F_ 1024
#define W_ 512
#define HD_ 128
#define FW 524288L  // F_*W_
#define PF_ 1026
#define PW_ 514

typedef __bf16 bf16_t;
typedef __bf16 bf16x8 __attribute__((ext_vector_type(8)));
typedef __bf16 bf16x4 __attribute__((ext_vector_type(4)));
typedef float f32x4 __attribute__((ext_vector_type(4)));

__device__ __forceinline__ void gload16(const void* g, void* l) {
    __builtin_amdgcn_global_load_lds(
        (const __attribute__((address_space(1))) unsigned int*)g,
        (__attribute__((address_space(3))) unsigned int*)l,
        16, 0, 0);
}

__device__ __forceinline__ float gelu_f(float v) {
    return 0.5f * v * (1.0f + erff(v * 0.70710678118f));
}

// bijective XCD-chunked block swizzle (requires nwg % 8 == 0)
__device__ __forceinline__ void xcd_swz3(int& bx, int& by, int& bz) {
    const int nwg = gridDim.x * gridDim.y * gridDim.z;
    int orig = blockIdx.x + gridDim.x * (blockIdx.y + gridDim.y * blockIdx.z);
    orig = (orig & 7) * (nwg >> 3) + (orig >> 3);
    bx = orig % gridDim.x;
    int t = orig / gridDim.x;
    by = t % gridDim.y;
    bz = t / gridDim.y;
}

// ---------------- fused prep: cvtw | pad_stage | aprep | border-zero ----------------
__global__ __launch_bounds__(256)
void prep_k(const float* __restrict__ q_pw, const float* __restrict__ k_pw,
            const float* __restrict__ v_pw, const float* __restrict__ o_pw,
            const float* __restrict__ x,
            const float* __restrict__ qw, const float* __restrict__ kw,
            const float* __restrict__ vw, const float* __restrict__ ow,
            const float* __restrict__ c1w, const float* __restrict__ c2w,
            const float* __restrict__ qb, const float* __restrict__ kb,
            const float* __restrict__ vb,
            bf16_t* __restrict__ W4, bf16_t* __restrict__ px,
            bf16_t* __restrict__ a_qkv, bf16_t* __restrict__ a_op,
            bf16_t* __restrict__ a_c1, bf16_t* __restrict__ a_c2,
            float* __restrict__ bias_qkv,
            bf16_t* __restrict__ p8a, bf16_t* __restrict__ p8b, bf16_t* __restrict__ p32)
{
    const int bid = blockIdx.x, tid = threadIdx.x;
    if (bid < 32768) {
        long i = (long)bid * 256 + tid;
        const int wsel = (int)(i >> 21);
        const long off = i & 2097151L;
        const float* src = (wsel == 0) ? q_pw : (wsel == 1) ? k_pw : (wsel == 2) ? v_pw : o_pw;
        float4 v = ((const float4*)src)[off];
        bf16x4 r = { (bf16_t)v.x, (bf16_t)v.y, (bf16_t)v.z, (bf16_t)v.w };
        *(bf16x4*)&W4[i * 4] = r;
    } else if (bid < 36889) {
        long i = (long)(bid - 32768) * 256 + tid;
        if (i >= (long)B_ * PF_ * PW_) return;
        int wc = (int)(i % PW_);
        long t = i / PW_;
        int fr = (int)(t % PF_);
        int b  = (int)(t / PF_);
        bf16x8 v = {};
        if (fr >= 1 && fr <= F_ && wc >= 1 && wc <= W_) {
            const float* s = x + (long)b * 8 * FW + (long)(fr - 1) * W_ + (wc - 1);
            #pragma unroll
            for (int c = 0; c < 8; ++c) v[c] = (bf16_t)s[c * FW];
        }
        *(bf16x8*)&px[i * 8] = v;
    } else if (bid < 36961) {
        int sub = bid - 36889;
        int mode = sub / 18;
        int i = (sub % 18) * 256 + tid;
        if (mode == 0) {              // qkv: [3][32][32]
            if (i < 3072) {
                int k = i & 31, co = (i >> 5) & 31, df = i >> 10;
                int tap = k >> 3, ci = k & 7;
                float v = 0.f;
                if (tap < 3) {
                    if (co < 8)       v = qw[((co * 8 + ci) * 3 + df) * 3 + tap];
                    else if (co < 16) v = kw[(((co - 8) * 8 + ci) * 3 + df) * 3 + tap];
                    else if (co < 24) v = vw[(((co - 16) * 8 + ci) * 3 + df) * 3 + tap];
                }
                a_qkv[i] = (bf16_t)v;
            }
            if (i < 32) bias_qkv[i] = (i < 8) ? qb[i] : (i < 16) ? kb[i - 8] : (i < 24) ? vb[i - 16] : 0.f;
        } else if (mode == 1) {       // oproj: [3][16][64]
            if (i < 3072) {
                int k = i & 63, co = (i >> 6) & 15, df = i >> 10;
                int src = k >> 5, r = k & 31, tap = r >> 3, ci = src * 8 + (r & 7);
                float v = 0.f;
                if (co < 8 && tap < 3) v = ow[((co * 16 + ci) * 3 + df) * 3 + tap];
                a_op[i] = (bf16_t)v;
            }
        } else if (mode == 2) {       // c1: [3][32][32]
            if (i < 3072) {
                int k = i & 31, co = (i >> 5) & 31, df = i >> 10;
                int tap = k >> 3, ci = k & 7;
                float v = (tap < 3) ? c1w[((co * 8 + ci) * 3 + df) * 3 + tap] : 0.f;
                a_c1[i] = (bf16_t)v;
            }
        } else {                      // c2: [3][16][96]
            if (i < 4608) {
                int k = i % 96, co = (i / 96) & 15, df = i / (96 * 16);
                int tap = k >> 5, ci = k & 31;
                float v = (co < 8) ? c2w[((co * 32 + ci) * 3 + df) * 3 + tap] : 0.f;
                a_c2[i] = (bf16_t)v;
            }
        }
    } else {
        int i = (bid - 36961) * 256 + tid;
        if (i >= 2 * 3076) return;
        int b = i / 3076, p = i % 3076;
        int fr, wc;
        if (p < 514)       { fr = 0;    wc = p; }
        else if (p < 1028) { fr = 1025; wc = p - 514; }
        else if (p < 2052) { fr = 1 + (p - 1028); wc = 0; }
        else               { fr = 1 + (p - 2052); wc = 513; }
        long pix = ((long)b * PF_ + fr) * PW_ + wc;
        bf16x8 z = {};
        *(bf16x8*)&p8a[pix * 8] = z;
        *(bf16x8*)&p8b[pix * 8] = z;
        #pragma unroll
        for (int k = 0; k < 4; ++k) *(bf16x8*)&p32[pix * 32 + k * 8] = z;
    }
}

// ---------------- MFMA shift-GEMM conv ----------------
template<int CIN, int KSTEPS, int MFRAGS, int DUAL, int EPI, int RESBF>
__global__ __launch_bounds__(256)
void convg_k(const bf16_t* __restrict__ px0, const bf16_t* __restrict__ px1,
             const bf16_t* __restrict__ Ab, const float* __restrict__ bias,
             const void* __restrict__ resid, void* __restrict__ outp)
{
    const int f = blockIdx.y, b = blockIdx.z;
    const int tid = threadIdx.x, lane = tid & 63, wid = tid >> 6;
    const int l15 = lane & 15, l4 = lane >> 4;
    const int wbase = blockIdx.x * 256 + wid * 64;
    const int KW = KSTEPS * 32, M16 = MFRAGS * 16;

    bf16x8 af[3][MFRAGS][KSTEPS];
    #pragma unroll
    for (int df = 0; df < 3; ++df)
        #pragma unroll
        for (int mf = 0; mf < MFRAGS; ++mf)
            #pragma unroll
            for (int kk = 0; kk < KSTEPS; ++kk)
                af[df][mf][kk] = *(const bf16x8*)&Ab[(long)(df * M16 + mf * 16 + l15) * KW + kk * 32 + l4 * 8];

    f32x4 acc[MFRAGS][4];
    #pragma unroll
    for (int mf = 0; mf < MFRAGS; ++mf)
        #pragma unroll
        for (int nf = 0; nf < 4; ++nf)
            acc[mf][nf] = (f32x4){0.f, 0.f, 0.f, 0.f};

    #pragma unroll
    for (int df = 0; df < 3; ++df) {
        const long rowb = ((long)(b * PF_ + f + df)) * PW_ * CIN;
        #pragma unroll
        for (int nf = 0; nf < 4; ++nf) {
            const int wp = wbase + nf * 16 + l15;
            #pragma unroll
            for (int kk = 0; kk < KSTEPS; ++kk) {
                const bf16_t* src = (DUAL && kk == 1) ? px1 : px0;
                long addr = (CIN == 8) ? rowb + (long)(wp + l4) * 8
                                       : rowb + (long)(wp + kk) * 32 + l4 * 8;
                bf16x8 bv = *(const bf16x8*)&src[addr];
                #pragma unroll
                for (int mf = 0; mf < MFRAGS; ++mf)
                    acc[mf][nf] = __builtin_amdgcn_mfma_f32_16x16x32_bf16(
                        af[df][mf][kk], bv, acc[mf][nf], 0, 0, 0);
            }
        }
    }

    #pragma unroll
    for (int mf = 0; mf < MFRAGS; ++mf) {
        #pragma unroll
        for (int nf = 0; nf < 4; ++nf) {
            const int wp = wbase + nf * 16 + l15;
            if (EPI == 2) {
                const int cob = mf * 16 + l4 * 4;
                bf16x4 ov;
                #pragma unroll
                for (int r = 0; r < 4; ++r)
                    ov[r] = (bf16_t)gelu_f(acc[mf][nf][r] + bias[cob + r]);
                *(bf16x4*)&((bf16_t*)outp)[(((long)(b * PF_ + f + 1)) * PW_ + wp + 1) * 32 + cob] = ov;
            } else {
                #pragma unroll
                for (int r = 0; r < 4; ++r) {
                    const int co = mf * 16 + l4 * 4 + r;
                    float v = acc[mf][nf][r];
                    if (EPI == 0) {
                        if (co < 24)
                            ((bf16_t*)outp)[((long)(b * 24 + co)) * FW + (long)f * W_ + wp] = (bf16_t)(v + bias[co]);
                    } else {
                        if (co < 8) {
                            long oi = ((long)(b * 8 + co)) * FW + (long)f * W_ + wp;
                            float rv = RESBF ? (float)((const bf16_t*)resid)[oi]
                                             : ((const float*)resid)[oi];
                            ((bf16_t*)outp)[oi] = (bf16_t)(v + bias[co] + rv);
                        }
                    }
                }
            }
        }
    }
}

// ---------------- bf16 MFMA GEMM: C = A(MxK) * B^T-stored(NxK) ----------------
template<int OUTBF>
__global__ __launch_bounds__(256, 4)
void gemm_mfma_k(const bf16_t* __restrict__ Ab, const bf16_t* __restrict__ Bb,
                 void* __restrict__ Cb,
                 int Kdim, int lda, int ldb, int ldc,
                 long sA, long sB, long sC_hi, long sC_lo, int zdivC, int aMod)
{
    __shared__ bf16_t sAt[8192];
    __shared__ bf16_t sBt[8192];

    int bx, by, bz;
    xcd_swz3(bx, by, bz);
    const int z = bz;
    const int m0 = by * 128;
    const int n0 = bx * 128;
    const int tid = threadIdx.x;
    const int lane = tid & 63, wid = tid >> 6;
    const int wr = (wid >> 1) * 64, wc = (wid & 1) * 64;
    const int l15 = lane & 15, l4 = lane >> 4;

    const bf16_t* A = Ab + (long)(z % aMod) * sA;
    const bf16_t* B = Bb + (long)z * sB;

    f32x4 acc[4][4];
    #pragma unroll
    for (int m = 0; m < 4; ++m)
        #pragma unroll
        for (int n = 0; n < 4; ++n)
            acc[m][n] = (f32x4){0.f, 0.f, 0.f, 0.f};

    const int grow = wid * 8 + (lane >> 3);
    const int gslot = lane & 7;

    for (int k0 = 0; k0 < Kdim; k0 += 64) {
        __syncthreads();
        #pragma unroll
        for (int r = 0; r < 4; ++r) {
            const int row = r * 32 + grow;
            gload16(A + (long)(m0 + row) * lda + k0 + ((gslot ^ (row & 7)) << 3),
                    sAt + r * 2048 + wid * 512);
        }
        #pragma unroll
        for (int r = 0; r < 4; ++r) {
            const int row = r * 32 + grow;
            gload16(B + (long)(n0 + row) * ldb + k0 + ((gslot ^ (row & 7)) << 3),
                    sBt + r * 2048 + wid * 512);
        }
        __syncthreads();

        bf16x8 afr[4][2], bfr[4][2];
        #pragma unroll
        for (int m = 0; m < 4; ++m) {
            const int row = wr + m * 16 + l15, swz = row & 7;
            afr[m][0] = *(const bf16x8*)&sAt[row * 64 + ((l4 ^ swz) << 3)];
            afr[m][1] = *(const bf16x8*)&sAt[row * 64 + (((4 + l4) ^ swz) << 3)];
        }
        #pragma unroll
        for (int n = 0; n < 4; ++n) {
            const int row = wc + n * 16 + l15, swz = row & 7;
            bfr[n][0] = *(const bf16x8*)&sBt[row * 64 + ((l4 ^ swz) << 3)];
            bfr[n][1] = *(const bf16x8*)&sBt[row * 64 + (((4 + l4) ^ swz) << 3)];
        }
        #pragma unroll
        for (int kk = 0; kk < 2; ++kk)
            #pragma unroll
            for (int m = 0; m < 4; ++m)
                #pragma unroll
                for (int n = 0; n < 4; ++n)
                    acc[m][n] = __builtin_amdgcn_mfma_f32_16x16x32_bf16(
                        afr[m][kk], bfr[n][kk], acc[m][n], 0, 0, 0);
    }

    const long zc = (long)(z / zdivC) * sC_hi + (long)(z % zdivC) * sC_lo;
    #pragma unroll
    for (int m = 0; m < 4; ++m) {
        #pragma unroll
        for (int n = 0; n < 4; ++n) {
            #pragma unroll
            for (int r = 0; r < 4; ++r) {
                int row = m0 + wr + m * 16 + l4 * 4 + r;
                int col = n0 + wc + n * 16 + l15;
                float v = acc[m][n][r];
                long cidx = zc + (long)row * ldc + col;
                if (OUTBF) ((bf16_t*)Cb)[cidx] = (bf16_t)v;
                else       ((float*)Cb)[cidx]  = v;
            }
        }
    }
}

// ---------------- merged q/k/v mclin GEMM (z = path*16 + bm), rope fused for q/k ----------------
__global__ __launch_bounds__(256, 4)
void qkvgemm_k(const bf16_t* __restrict__ W4, const bf16_t* __restrict__ XT,
               bf16_t* __restrict__ outp /* = QR base; KR/VL adjacent */)
{
    __shared__ bf16_t sAt[8192];
    __shared__ bf16_t sBt[8192];

    int bx, by, bz;
    xcd_swz3(bx, by, bz);
    const int zz = bz;                   // 0..47
    const int path = zz >> 4, bm = zz & 15;
    const bf16_t* A = W4 + (long)(path * 8 + (bm & 7)) * 1048576L;
    const bf16_t* B = XT + (long)zz * FW;   // [W][F], ldb = 1024
    const int m0 = by * 128;
    const int n0 = bx * 128;
    const int tid = threadIdx.x;
    const int lane = tid & 63, wid = tid >> 6;
    const int wr = (wid >> 1) * 64, wc = (wid & 1) * 64;
    const int l15 = lane & 15, l4 = lane >> 4;

    f32x4 acc[4][4];
    #pragma unroll
    for (int m = 0; m < 4; ++m)
        #pragma unroll
        for (int n = 0; n < 4; ++n)
            acc[m][n] = (f32x4){0.f, 0.f, 0.f, 0.f};

    const int grow = wid * 8 + (lane >> 3);
    const int gslot = lane & 7;

    for (int k0 = 0; k0 < 1024; k0 += 64) {
        __syncthreads();
        #pragma unroll
        for (int r = 0; r < 4; ++r) {
            const int row = r * 32 + grow;
            gload16(A + (long)(m0 + row) * 1024 + k0 + ((gslot ^ (row & 7)) << 3),
                    sAt + r * 2048 + wid * 512);
        }
        #pragma unroll
        for (int r = 0; r < 4; ++r) {
            const int row = r * 32 + grow;
            gload16(B + (long)(n0 + row) * 1024 + k0 + ((gslot ^ (row & 7)) << 3),
                    sBt + r * 2048 + wid * 512);
        }
        __syncthreads();

        bf16x8 afr[4][2], bfr[4][2];
        #pragma unroll
        for (int m = 0; m < 4; ++m) {
            const int row = wr + m * 16 + l15, swz = row & 7;
            afr[m][0] = *(const bf16x8*)&sAt[row * 64 + ((l4 ^ swz) << 3)];
            afr[m][1] = *(const bf16x8*)&sAt[row * 64 + (((4 + l4) ^ swz) << 3)];
        }
        #pragma unroll
        for (int n = 0; n < 4; ++n) {
            const int row = wc + n * 16 + l15, swz = row & 7;
            bfr[n][0] = *(const bf16x8*)&sBt[row * 64 + ((l4 ^ swz) << 3)];
            bfr[n][1] = *(const bf16x8*)&sBt[row * 64 + (((4 + l4) ^ swz) << 3)];
        }
        #pragma unroll
        for (int kk = 0; kk < 2; ++kk)
            #pragma unroll
            for (int m = 0; m < 4; ++m)
                #pragma unroll
                for (int n = 0; n < 4; ++n)
                    acc[m][n] = __builtin_amdgcn_mfma_f32_16x16x32_bf16(
                        afr[m][kk], bfr[n][kk], acc[m][n], 0, 0, 0);
    }

    if (path < 2) {
        const long base = (long)path * 8388608L + (((long)bm * 8 + by) * 512L) * 128L;
        #pragma unroll
        for (int m = 0; m < 4; ++m) {
            const int d0 = wr + m * 16 + l4 * 4;
            const float inv0 = __expf(-(float)(d0 >> 1) * 0.14391156507f);
            const float inv1 = __expf(-(float)((d0 >> 1) + 1) * 0.14391156507f);
            #pragma unroll
            for (int n = 0; n < 4; ++n) {
                const int col = n0 + wc + n * 16 + l15;
                float s0, c0, s1, c1;
                __sincosf((float)col * inv0, &s0, &c0);
                __sincosf((float)col * inv1, &s1, &c1);
                float v0 = acc[m][n][0], v1 = acc[m][n][1];
                float v2 = acc[m][n][2], v3 = acc[m][n][3];
                bf16x4 ov = { (bf16_t)(v0 * c0 - v1 * s0), (bf16_t)(v1 * c0 + v0 * s0),
                              (bf16_t)(v2 * c1 - v3 * s1), (bf16_t)(v3 * c1 + v2 * s1) };
                *(bf16x4*)&outp[base + (long)col * 128 + d0] = ov;
            }
        }
    } else {
        const long base = 16777216L + (long)bm * FW;
        #pragma unroll
        for (int m = 0; m < 4; ++m)
            #pragma unroll
            for (int n = 0; n < 4; ++n)
                #pragma unroll
                for (int r = 0; r < 4; ++r) {
                    int row = m0 + wr + m * 16 + l4 * 4 + r;
                    int col = n0 + wc + n * 16 + l15;
                    outp[base + (long)row * 512 + col] = (bf16_t)acc[m][n][r];
                }
    }
}

// ---------------- fused attention (64-row m-tiles, 4 blocks/CU) ----------------
// Phase A: 4 kc-tiles of S(64x128) + online row stats in LDS; write S.
// Phase B: re-read own S (L2-hot), P=exp(S-M) into LDS, PV MFMA, normalize by 1/sum.
__global__ __launch_bounds__(256, 4)
void attn_k(const bf16_t* __restrict__ QR, const bf16_t* __restrict__ KR,
            const bf16_t* __restrict__ VL, const float* __restrict__ prevb,
            float* __restrict__ Sout, bf16_t* __restrict__ AT)
{
    __shared__ bf16_t sA[4096];    // Q 64x64 / P 64x64, swizzled
    __shared__ bf16_t sB[8192];    // K/V 128x64, swizzled
    __shared__ float red[2][64][2];
    __shared__ float Mrun[64], Srun[64];

    int bx, by, bz;
    xcd_swz3(bx, by, bz);
    (void)by;
    const int z = bz;
    const int m0 = bx * 64;
    const bf16_t* Qb = QR + (long)z * 65536L;
    const bf16_t* Kb = KR + (long)z * 65536L;
    const bf16_t* Vb = VL + (long)z * 65536L;
    const float* prev = prevb + (long)z * 262144L;
    float* Sb = Sout + (long)z * 262144L;

    const int tid = threadIdx.x, lane = tid & 63, wid = tid >> 6;
    const int l15 = lane & 15, l4 = lane >> 4;
    const int wr = (wid >> 1) * 32, wc = (wid & 1) * 64;
    const int grow = wid * 8 + (lane >> 3);
    const int gslot = lane & 7;

    if (tid < 64) { Mrun[tid] = -1e30f; Srun[tid] = 0.f; }

    // ---------------- phase A: S = QK^T/32 + prev ----------------
    for (int kc = 0; kc < 4; ++kc) {
        f32x4 acc[2][4];
        #pragma unroll
        for (int m = 0; m < 2; ++m)
            #pragma unroll
            for (int n = 0; n < 4; ++n)
                acc[m][n] = (f32x4){0.f, 0.f, 0.f, 0.f};

        #pragma unroll
        for (int k0 = 0; k0 < 128; k0 += 64) {
            __syncthreads();
            #pragma unroll
            for (int r = 0; r < 2; ++r) {
                const int row = r * 32 + grow;
                gload16(Qb + (long)(m0 + row) * 128 + k0 + ((gslot ^ (row & 7)) << 3),
                        sA + r * 2048 + wid * 512);
            }
            #pragma unroll
            for (int r = 0; r < 4; ++r) {
                const int row = r * 32 + grow;
                gload16(Kb + (long)(kc * 128 + row) * 128 + k0 + ((gslot ^ (row & 7)) << 3),
                        sB + r * 2048 + wid * 512);
            }
            __syncthreads();

            bf16x8 afr[2][2], bfr[4][2];
            #pragma unroll
            for (int m = 0; m < 2; ++m) {
                const int row = wr + m * 16 + l15, swz = row & 7;
                afr[m][0] = *(const bf16x8*)&sA[row * 64 + ((l4 ^ swz) << 3)];
                afr[m][1] = *(const bf16x8*)&sA[row * 64 + (((4 + l4) ^ swz) << 3)];
            }
            #pragma unroll
            for (int n = 0; n < 4; ++n) {
                const int row = wc + n * 16 + l15, swz = row & 7;
                bfr[n][0] = *(const bf16x8*)&sB[row * 64 + ((l4 ^ swz) << 3)];
                bfr[n][1] = *(const bf16x8*)&sB[row * 64 + (((4 + l4) ^ swz) << 3)];
            }
            __builtin_amdgcn_s_setprio(1);
            #pragma unroll
            for (int kk = 0; kk < 2; ++kk)
                #pragma unroll
                for (int m = 0; m < 2; ++m)
                    #pragma unroll
                    for (int n = 0; n < 4; ++n)
                        acc[m][n] = __builtin_amdgcn_mfma_f32_16x16x32_bf16(
                            afr[m][kk], bfr[n][kk], acc[m][n], 0, 0, 0);
            __builtin_amdgcn_s_setprio(0);
        }

        // epilogue: add prev, store S, per-row stats over this 128-col tile
        #pragma unroll
        for (int m = 0; m < 2; ++m) {
            #pragma unroll
            for (int n = 0; n < 4; ++n) {
                #pragma unroll
                for (int r = 0; r < 4; ++r) {
                    int row = m0 + wr + m * 16 + l4 * 4 + r;
                    int col = kc * 128 + wc + n * 16 + l15;
                    float v = acc[m][n][r] * 0.03125f + prev[(long)row * 512 + col];
                    acc[m][n][r] = v;
                    Sb[(long)row * 512 + col] = v;
                }
            }
        }
        #pragma unroll
        for (int m = 0; m < 2; ++m) {
            #pragma unroll
            for (int r = 0; r < 4; ++r) {
                float mx = -1e30f;
                #pragma unroll
                for (int n = 0; n < 4; ++n) mx = fmaxf(mx, acc[m][n][r]);
                #pragma unroll
                for (int o = 1; o <= 8; o <<= 1) mx = fmaxf(mx, __shfl_xor(mx, o, 64));
                float se = 0.f;
                #pragma unroll
                for (int n = 0; n < 4; ++n) se += __expf(acc[m][n][r] - mx);
                #pragma unroll
                for (int o = 1; o <= 8; o <<= 1) se += __shfl_xor(se, o, 64);
                if (l15 == 0) {
                    int row = wr + m * 16 + l4 * 4 + r;
                    red[wid & 1][row][0] = mx;
                    red[wid & 1][row][1] = se;
                }
            }
        }
        __syncthreads();
        if (tid < 64) {
            float ma = red[0][tid][0], sa = red[0][tid][1];
            float mb = red[1][tid][0], sb = red[1][tid][1];
            float mt = fmaxf(ma, mb);
            float st = sa * __expf(ma - mt) + sb * __expf(mb - mt);
            float M0 = Mrun[tid], S0 = Srun[tid];
            float M1 = fmaxf(M0, mt);
            Srun[tid] = S0 * __expf(M0 - M1) + st * __expf(mt - M1);
            Mrun[tid] = M1;
        }
    }
    __syncthreads();

    // ---------------- phase B: O = softmax(S) @ V ----------------
    f32x4 oacc[2][4];
    #pragma unroll
    for (int m = 0; m < 2; ++m)
        #pragma unroll
        for (int n = 0; n < 4; ++n)
            oacc[m][n] = (f32x4){0.f, 0.f, 0.f, 0.f};

    const int prow0 = tid >> 4, pl = tid & 15;

    for (int kt = 0; kt < 512; kt += 64) {
        __syncthreads();
        #pragma unroll
        for (int p = 0; p < 4; ++p) {
            const int row = p * 16 + prow0;
            float4 v = *(const float4*)(Sb + (long)(m0 + row) * 512 + kt + pl * 4);
            float mr = Mrun[row];
            bf16x4 e = { (bf16_t)__expf(v.x - mr), (bf16_t)__expf(v.y - mr),
                         (bf16_t)__expf(v.z - mr), (bf16_t)__expf(v.w - mr) };
            *(bf16x4*)((char*)sA + row * 128 + ((((pl >> 1) ^ (row & 7))) << 4) + (pl & 1) * 8) = e;
        }
        #pragma unroll
        for (int r = 0; r < 4; ++r) {
            const int row = r * 32 + grow;
            gload16(Vb + (long)row * 512 + kt + ((gslot ^ (row & 7)) << 3),
                    sB + r * 2048 + wid * 512);
        }
        __syncthreads();

        bf16x8 afr[2][2], bfr[4][2];
        #pragma unroll
        for (int m = 0; m < 2; ++m) {
            const int row = wr + m * 16 + l15, swz = row & 7;
            afr[m][0] = *(const bf16x8*)&sA[row * 64 + ((l4 ^ swz) << 3)];
            afr[m][1] = *(const bf16x8*)&sA[row * 64 + (((4 + l4) ^ swz) << 3)];
        }
        #pragma unroll
        for (int n = 0; n < 4; ++n) {
            const int row = wc + n * 16 + l15, swz = row & 7;
            bfr[n][0] = *(const bf16x8*)&sB[row * 64 + ((l4 ^ swz) << 3)];
            bfr[n][1] = *(const bf16x8*)&sB[row * 64 + (((4 + l4) ^ swz) << 3)];
        }
        __builtin_amdgcn_s_setprio(1);
        #pragma unroll
        for (int kk = 0; kk < 2; ++kk)
            #pragma unroll
            for (int m = 0; m < 2; ++m)
                #pragma unroll
                for (int n = 0; n < 4; ++n)
                    oacc[m][n] = __builtin_amdgcn_mfma_f32_16x16x32_bf16(
                        afr[m][kk], bfr[n][kk], oacc[m][n], 0, 0, 0);
        __builtin_amdgcn_s_setprio(0);
    }

    const long base = (long)(z >> 3) * FW + (long)(z & 7) * 128L;
    #pragma unroll
    for (int m = 0; m < 2; ++m) {
        #pragma unroll
        for (int n = 0; n < 4; ++n) {
            #pragma unroll
            for (int r = 0; r < 4; ++r) {
                const int row = wr + m * 16 + l4 * 4 + r;
                const int col = wc + n * 16 + l15;
                float v = oacc[m][n][r] / Srun[row];
                AT[base + (long)(m0 + row) * 1024 + col] = (bf16_t)v;
            }
        }
    }
}

// ---------------- transpose+cvt: QKV planar [b][24][F][W] -> XT48 [path*16+bm][W][F] ----------------
__global__ __launch_bounds__(256)
void tcvt_k(const bf16_t* __restrict__ in, bf16_t* __restrict__ outp)
{
    __shared__ float tile[32][33];
    const int w0 = blockIdx.x * 32, f0 = blockIdx.y * 32;
    const int z = blockIdx.z;              // 0..47
    const int path = z >> 4, bm = z & 15;
    const int inSlice = (bm >> 3) * 24 + path * 8 + (bm & 7);
    const long ibase = (long)inSlice * FW;
    const long obase = (long)z * FW;
    const int tx = threadIdx.x & 31, ty = threadIdx.x >> 5;
    #pragma unroll
    for (int i = 0; i < 4; ++i)
        tile[ty + i * 8][tx] = (float)in[ibase + (long)(f0 + ty + i * 8) * W_ + w0 + tx];
    __syncthreads();
    #pragma unroll
    for (int i = 0; i < 4; ++i)
        outp[obase + (long)(w0 + ty + i * 8) * F_ + f0 + tx] = (bf16_t)tile[tx][ty + i * 8];
}

// ---------------- depthwise o_dw mix (bf16 in) -> channels-last bf16 ----------------
__global__ __launch_bounds__(256)
void odw_k(const bf16_t* __restrict__ t, const float* __restrict__ dw, bf16_t* __restrict__ px)
{
    long i = (long)blockIdx.x * 256 + threadIdx.x;
    int w = (int)(i & (W_ - 1));
    long q = i >> 9;
    int f = (int)(q & (F_ - 1));
    int b = (int)(q >> 10);
    const bf16_t* s = t + (long)b * 8 * FW + (long)f * W_ + w;
    float tv[8];
    #pragma unroll
    for (int c = 0; c < 8; ++c) tv[c] = (float)s[c * FW];
    bf16x8 o;
    #pragma unroll
    for (int d = 0; d < 8; ++d) {
        float a = 0.f;
        #pragma unroll
        for (int c = 0; c < 8; ++c) a += tv[c] * dw[d * 8 + c];
        o[d] = (bf16_t)a;
    }
    *(bf16x8*)&px[(((long)b * PF_ + f + 1) * PW_ + w + 1) * 8] = o;
}

// ---------------- multichannel layernorm over F axis ----------------
template<typename TIN, int O1BF>
__global__ __launch_bounds__(256)
void mcln_k(const TIN* __restrict__ in, const float* __restrict__ gam,
            const float* __restrict__ bet, void* __restrict__ o1, float* __restrict__ o2,
            bf16_t* __restrict__ px)
{
    int wi = threadIdx.x & 31, fg = threadIdx.x >> 5;
    int w0 = blockIdx.x * 32;
    int c = blockIdx.y, b = blockIdx.z;
    long base = ((long)b * C_ + c) * FW + w0 + wi;
    float s = 0.f, q = 0.f;
    for (int f = fg; f < F_; f += 8) {
        float v = (float)in[base + (long)f * W_];
        s += v; q += v * v;
    }
    __shared__ float rs[8][33], rq[8][33];
    __shared__ float mu_s[32], inv_s[32];
    rs[fg][wi] = s; rq[fg][wi] = q;
    __syncthreads();
    if (fg == 0) {
        float ts = 0.f, tq = 0.f;
        for (int g = 0; g < 8; ++g) { ts += rs[g][wi]; tq += rq[g][wi]; }
        float mu = ts * (1.0f / F_);
        float var = tq * (1.0f / F_) - mu * mu;
        mu_s[wi] = mu;
        inv_s[wi] = rsqrtf(var + 1e-5f);
    }
    __syncthreads();
    float mu = mu_s[wi], inv = inv_s[wi];
    for (int f = fg; f < F_; f += 8) {
        float v = (float)in[base + (long)f * W_];
        float r = (v - mu) * inv * gam[c * F_ + f] + bet[c * F_ + f];
        long oi = base + (long)f * W_;
        if (O1BF) ((bf16_t*)o1)[oi] = (bf16_t)r;
        else      ((float*)o1)[oi]  = r;
        if (o2) o2[oi] = r;
        if (px) px[(((long)b * PF_ + f + 1) * PW_ + (w0 + wi) + 1) * 8 + c] = (bf16_t)r;
    }
}

extern "C" void kernel_launch(void* const* d_in, const int* in_sizes, int n_in,
                              void* d_out, int out_size, void* d_ws, size_t ws_size,
                              hipStream_t stream) {
    (void)in_sizes; (void)n_in; (void)out_size; (void)ws_size;
    const float* x        = (const float*)d_in[0];
    const float* prev_qk  = (const float*)d_in[1];
    const float* qconv_w  = (const float*)d_in[2];
    const float* qconv_b  = (const float*)d_in[3];
    const float* q_pw     = (const float*)d_in[4];
    const float* kconv_w  = (const float*)d_in[5];
    const float* kconv_b  = (const float*)d_in[6];
    const float* k_pw     = (const float*)d_in[7];
    const float* vconv_w  = (const float*)d_in[8];
    const float* vconv_b  = (const float*)d_in[9];
    const float* v_pw     = (const float*)d_in[10];
    const float* o_pw     = (const float*)d_in[11];
    const float* o_dw     = (const float*)d_in[12];
    const float* oproj_w  = (const float*)d_in[13];
    const float* oproj_b  = (const float*)d_in[14];
    const float* n1_w     = (const float*)d_in[15];
    const float* n1_b     = (const float*)d_in[16];
    const float* c1_w     = (const float*)d_in[17];
    const float* c1_b     = (const float*)d_in[18];
    const float* c2_w     = (const float*)d_in[19];
    const float* c2_b     = (const float*)d_in[20];
    const float* n2_w     = (const float*)d_in[21];
    const float* n2_b     = (const float*)d_in[22];

    float* out    = (float*)d_out;
    float* qk_out = out + 16777216L;

    // -------- workspace layout (~338.5 MB) --------
    char* wsb = (char*)d_ws;
    bf16_t* PX8  = (bf16_t*)(wsb + 0L);            // 16,876,032   A..F
    bf16_t* W4   = (bf16_t*)(wsb + 16876032L);     // 67,108,864   A..E
    bf16_t* QR   = (bf16_t*)(wsb + 83984896L);     // 16,777,216   C..D
    bf16_t* KR   = (bf16_t*)(wsb + 100762112L);    // 16,777,216   C..D
    bf16_t* VL   = (bf16_t*)(wsb + 117539328L);    // 16,777,216   C..D
    bf16_t* XT48 = (bf16_t*)(wsb + 134316544L);    // 50,331,648   C (dead after qkvgemm)
    bf16_t* HIDb = (bf16_t*)(wsb + 134316544L);    //   reuse XT48 head: 16,777,216  G..H
    bf16_t* QKV  = (bf16_t*)(wsb + 184648192L);    // 50,331,648   B..C (tcvt)
    bf16_t* AT   = (bf16_t*)(wsb + 184648192L);    //   reuse QKV head: 16,777,216   D..E
    bf16_t* F1b  = (bf16_t*)(wsb + 201425408L);    //   reuse QKV mid:  16,777,216   E
    bf16_t* PRE  = (bf16_t*)(wsb + 218202624L);    //   reuse QKV tail: 16,777,216   F..H
    bf16_t* PXA2 = (bf16_t*)(wsb + 234979840L);    // 16,875,776 fresh  (borders@prep) E..F
    bf16_t* PXH  = (bf16_t*)(wsb + 251855616L);    // 16,875,776 fresh  (borders@prep) G..H
    bf16_t* PXC1 = (bf16_t*)(wsb + 268731392L);    // 67,502,592 fresh  (borders@prep) H
    bf16_t* ABQ  = (bf16_t*)(wsb + 336233984L);
    bf16_t* ABO  = (bf16_t*)(wsb + 336233984L + 16384L);
    bf16_t* ABC1 = (bf16_t*)(wsb + 336233984L + 32768L);
    bf16_t* ABC2 = (bf16_t*)(wsb + 336233984L + 49152L);
    float*  BQKV = (float*) (wsb + 336233984L + 65536L);

    const dim3 cvgrid(2, F_, B_);
    const dim3 tgrid(16, 32, 48);

    // ---- A: fused prep ----
    prep_k<<<36986, 256, 0, stream>>>(q_pw, k_pw, v_pw, o_pw, x,
                                      qconv_w, kconv_w, vconv_w, oproj_w, c1_w, c2_w,
                                      qconv_b, kconv_b, vconv_b,
                                      W4, PX8, ABQ, ABO, ABC1, ABC2, BQKV,
                                      PXA2, PXH, PXC1);

    // ---- B: fused q/k/v conv (M=24) ----
    convg_k<8, 1, 2, 0, 0, 0><<<cvgrid, 256, 0, stream>>>(PX8, nullptr, ABQ, BQKV, nullptr, QKV);

    // ---- C: transpose once; merged q/k/v mclin (rope fused) ----
    tcvt_k<<<tgrid, 256, 0, stream>>>(QKV, XT48);
    qkvgemm_k<<<dim3(4, 8, 48), 256, 0, stream>>>(W4, XT48, QR);

    // ---- D: fused attention (QK^T + softmax + PV; 64-row tiles, 4 blocks/CU) ----
    attn_k<<<dim3(8, 1, 128), 256, 0, stream>>>(QR, KR, VL, prev_qk, qk_out, AT);

    // ---- E: o linear (bf16 W4, bf16 out) + depthwise mix ----
    gemm_mfma_k<1><<<dim3(4, 8, 16), 256, 0, stream>>>(W4 + 25165824L, AT, F1b,
        F_, F_, F_, W_, 1048576L, 524288L, 524288L, 0L, 1, 8);
    odw_k<<<4096, 256, 0, stream>>>(F1b, o_dw, PXA2);

    // ---- F: oproj conv (x ++ a2) + x residual -> pre1 (bf16) ----
    convg_k<8, 2, 1, 1, 1, 0><<<cvgrid, 256, 0, stream>>>(PX8, PXA2, ABO, oproj_b, x, PRE);

    // ---- G: hid = mcln(pre1) -> HIDb bf16 + PXH channels-last bf16 ----
    mcln_k<bf16_t, 1><<<dim3(16, 8, 2), 256, 0, stream>>>(PRE, n1_w, n1_b, HIDb, nullptr, PXH);

    // ---- H: ffn ----
    convg_k<8, 1, 2, 0, 2, 0><<<cvgrid, 256, 0, stream>>>(PXH, nullptr, ABC1, c1_b, nullptr, PXC1);
    convg_k<32, 3, 1, 0, 1, 1><<<cvgrid, 256, 0, stream>>>(PXC1, nullptr, ABC2, c2_b, HIDb, PRE);
    mcln_k<bf16_t, 0><<<dim3(16, 8, 2), 256, 0, stream>>>(PRE, n2_w, n2_b, out, out + 8388608L, nullptr);
}